// Round 1
// baseline (454.514 us; speedup 1.0000x reference)
//
#include <hip/hip_runtime.h>
#include <hip/hip_bf16.h>
#include <stdint.h>

// AdditiveAttention: B=32, S=4096, H=512, A=256
// d_out = [context: 32*512][attn: 32*4096]  (fp32)

typedef __attribute__((ext_vector_type(4))) float f32x4;
typedef __attribute__((ext_vector_type(8))) short short8;

#define B_  32
#define S_  4096
#define H_  512
#define A_  256

// ---- workspace layout (bytes) ----
#define WS_WT     0            // bf16 W_enc^T [256][512] : 262144 B
#define WS_BIAS   262144       // fp32 [32][256]          : 32768 B
#define WS_SCORES 294912       // fp32 [32][4096]         : 524288 B
#define WS_PART   819200       // fp32 [32][32][512]      : 2097152 B  (total ~2.79 MiB)

static __device__ __forceinline__ short f2bf(float f) {
  // RNE float->bf16
  union { float f; uint32_t u; } v; v.f = f;
  uint32_t r = (v.u + 0x7FFFu + ((v.u >> 16) & 1u)) >> 16;
  return (short)(uint16_t)r;
}

static __device__ __forceinline__ void gload_lds16(const void* g, void* l) {
  // async global->LDS, 16B per lane; LDS dest = base + lane*16
  __builtin_amdgcn_global_load_lds((const __attribute__((address_space(1))) void*)g,
                                   (__attribute__((address_space(3))) void*)l,
                                   16, 0, 0);
}

// ---------------- kernel 0: prep (dec projection + W_enc transpose/cvt) ---------
__global__ void prep_kernel(const float* __restrict__ dh,
                            const float* __restrict__ W_enc,
                            const float* __restrict__ b_enc,
                            const float* __restrict__ W_dec,
                            const float* __restrict__ b_dec,
                            unsigned short* __restrict__ WT,
                            float* __restrict__ bias) {
  int tid = threadIdx.x;
  if (blockIdx.x < 32) {
    // bias[b][a] = b_enc[a] + b_dec[a] + sum_k dh[b][k]*W_dec[k][a]
    int b = blockIdx.x;
    float s = b_enc[tid] + b_dec[tid];
    const float* dhb = dh + (size_t)b * H_;
    #pragma unroll 8
    for (int k = 0; k < H_; ++k)
      s = fmaf(dhb[k], W_dec[(size_t)k * A_ + tid], s);
    bias[b * A_ + tid] = s;
  } else {
    // WT[n][k] = bf16(W_enc[k][n])
    int t = (blockIdx.x - 32) * 256 + tid;   // 0..8191
    #pragma unroll
    for (int i = 0; i < 16; ++i) {
      int idx = t + i * 8192;                 // 0..131071, coalesced read
      int k = idx >> 8, n = idx & 255;
      WT[(size_t)n * H_ + k] = (unsigned short)f2bf(W_enc[idx]);
    }
  }
}

// ---------------- kernel 1: scores GEMM (bf16 MFMA, fused tanh·W_e) ------------
// grid: 1024 blocks, each: 128 rows (one b's s-chunk) x all 256 cols.
// 4 waves, each wave = 32 rows x 256 cols (2 m-tiles x 16 n-tiles of 16x16x32).
__global__ __launch_bounds__(256, 2) void scores_gemm(
    const float* __restrict__ enc,
    const unsigned short* __restrict__ WT,
    const float* __restrict__ bias,
    const float* __restrict__ We,
    float* __restrict__ scores) {
  __shared__ __align__(16) unsigned short Bt[256 * 32];  // 16 KiB: B-tile [n][k]

  const int tid  = threadIdx.x;
  const int wave = tid >> 6, lane = tid & 63;
  const int lm   = lane & 15, lq = lane >> 4;
  const int row0 = blockIdx.x * 128;
  const int b    = blockIdx.x >> 5;          // 32 blocks per batch (4096/128)

  f32x4 acc[2][16];
  #pragma unroll
  for (int mt = 0; mt < 2; ++mt)
    #pragma unroll
    for (int nt = 0; nt < 16; ++nt)
      acc[mt][nt] = (f32x4){0.f, 0.f, 0.f, 0.f};

  // A fragment source: row = row0 + wave*32 + mt*16 + lm, k = k0 + lq*8 .. +8
  size_t aoff[2];
  #pragma unroll
  for (int mt = 0; mt < 2; ++mt)
    aoff[mt] = (size_t)(row0 + wave * 32 + mt * 16 + lm) * H_ + lq * 8;

  float4 ca[2][2];
  #pragma unroll
  for (int mt = 0; mt < 2; ++mt) {
    const float* ap = enc + aoff[mt];
    ca[mt][0] = *(const float4*)ap;
    ca[mt][1] = *(const float4*)(ap + 4);
  }

  const int bn = (wave * 4) * 16 + (lane >> 2);  // base n for this wave's staging
  const int kb = (lane & 3) * 8;                 // k sub-offset (bf16 elems)

  for (int k0 = 0; k0 < H_; k0 += 32) {
    __syncthreads();  // WAR: previous iter's fragment reads of Bt done
    // stage B tile [256 n][32 k] bf16: 16 chunks of 1 KiB, 4 per wave
    #pragma unroll
    for (int c = 0; c < 4; ++c) {
      int n = bn + c * 16;
      gload_lds16(WT + (size_t)n * H_ + k0 + kb,
                  (char*)Bt + (size_t)(wave * 4 + c) * 1024);
    }
    // prefetch next A fragments (in flight alongside B staging)
    float4 na[2][2];
    const int kn = k0 + 32;
    if (kn < H_) {
      #pragma unroll
      for (int mt = 0; mt < 2; ++mt) {
        const float* ap = enc + aoff[mt] + kn;
        na[mt][0] = *(const float4*)ap;
        na[mt][1] = *(const float4*)(ap + 4);
      }
    }
    __syncthreads();  // B tile visible

    short8 af[2];
    #pragma unroll
    for (int mt = 0; mt < 2; ++mt) {
      af[mt][0] = f2bf(ca[mt][0].x); af[mt][1] = f2bf(ca[mt][0].y);
      af[mt][2] = f2bf(ca[mt][0].z); af[mt][3] = f2bf(ca[mt][0].w);
      af[mt][4] = f2bf(ca[mt][1].x); af[mt][5] = f2bf(ca[mt][1].y);
      af[mt][6] = f2bf(ca[mt][1].z); af[mt][7] = f2bf(ca[mt][1].w);
    }
    #pragma unroll
    for (int nt = 0; nt < 16; ++nt) {
      // B frag: n = nt*16+lm, k = lq*8.. -> [n][k] row 64B, 16B aligned
      short8 bf = *(const short8*)((const char*)Bt + (size_t)(nt * 16 + lm) * 64 + lq * 16);
      #pragma unroll
      for (int mt = 0; mt < 2; ++mt)
        acc[mt][nt] = __builtin_amdgcn_mfma_f32_16x16x32_bf16(af[mt], bf, acc[mt][nt], 0, 0, 0);
    }
    if (kn < H_) {
      #pragma unroll
      for (int mt = 0; mt < 2; ++mt) { ca[mt][0] = na[mt][0]; ca[mt][1] = na[mt][1]; }
    }
  }

  // epilogue: score[row] = sum_col tanh(acc + bias[b][col]) * We[col]
  // C/D layout: col = lane&15, row = (lane>>4)*4 + reg   [m89/m91 verified]
  float psum[2][4] = {{0, 0, 0, 0}, {0, 0, 0, 0}};
  #pragma unroll
  for (int nt = 0; nt < 16; ++nt) {
    int col = nt * 16 + lm;
    float dp = bias[b * A_ + col];
    float wv = We[col];
    #pragma unroll
    for (int mt = 0; mt < 2; ++mt)
      #pragma unroll
      for (int r = 0; r < 4; ++r) {
        float x = acc[mt][nt][r] + dp;
        float e = __expf(2.0f * x);                       // v_exp_f32 path
        float t = 1.0f - 2.0f * __builtin_amdgcn_rcpf(e + 1.0f);  // tanh(x)
        psum[mt][r] = fmaf(t, wv, psum[mt][r]);
      }
  }
  // reduce over the 16 lanes of each column group (low 4 lane bits)
  #pragma unroll
  for (int o = 1; o < 16; o <<= 1)
    #pragma unroll
    for (int mt = 0; mt < 2; ++mt)
      #pragma unroll
      for (int r = 0; r < 4; ++r)
        psum[mt][r] += __shfl_xor(psum[mt][r], o, 64);
  if (lm == 0) {
    #pragma unroll
    for (int mt = 0; mt < 2; ++mt)
      #pragma unroll
      for (int r = 0; r < 4; ++r)
        scores[row0 + wave * 32 + mt * 16 + lq * 4 + r] = psum[mt][r];
  }
}

// ---------------- kernel 2: softmax over S per batch ---------------------------
__global__ void softmax_kernel(const float* __restrict__ scores,
                               float* __restrict__ attn) {
  int b = blockIdx.x, tid = threadIdx.x;
  int wave = tid >> 6, lane = tid & 63;
  const float4* sp = (const float4*)(scores + (size_t)b * S_);
  float4 v[4];
  #pragma unroll
  for (int i = 0; i < 4; ++i) v[i] = sp[tid + i * 256];

  float m = -1e30f;
  #pragma unroll
  for (int i = 0; i < 4; ++i) {
    m = fmaxf(m, fmaxf(fmaxf(v[i].x, v[i].y), fmaxf(v[i].z, v[i].w)));
  }
  #pragma unroll
  for (int o = 1; o < 64; o <<= 1) m = fmaxf(m, __shfl_xor(m, o, 64));
  __shared__ float redm[4];
  if (lane == 0) redm[wave] = m;
  __syncthreads();
  m = fmaxf(fmaxf(redm[0], redm[1]), fmaxf(redm[2], redm[3]));

  float sum = 0.f;
  float4 p[4];
  #pragma unroll
  for (int i = 0; i < 4; ++i) {
    p[i].x = __expf(v[i].x - m); p[i].y = __expf(v[i].y - m);
    p[i].z = __expf(v[i].z - m); p[i].w = __expf(v[i].w - m);
    sum += p[i].x + p[i].y + p[i].z + p[i].w;
  }
  #pragma unroll
  for (int o = 1; o < 64; o <<= 1) sum += __shfl_xor(sum, o, 64);
  __shared__ float reds[4];
  if (lane == 0) reds[wave] = sum;
  __syncthreads();
  float inv = 1.0f / (reds[0] + reds[1] + reds[2] + reds[3]);

  float4* op = (float4*)(attn + (size_t)b * S_);
  #pragma unroll
  for (int i = 0; i < 4; ++i) {
    float4 o4; o4.x = p[i].x * inv; o4.y = p[i].y * inv;
    o4.z = p[i].z * inv; o4.w = p[i].w * inv;
    op[tid + i * 256] = o4;
  }
}

// ---------------- kernel 3: context partials (attn-weighted row sum) -----------
// grid 1024 = 32 b x 32 chunks of 128 s-rows; 256 thr x float2 = one 2KiB row/iter
__global__ void ctx_partial(const float* __restrict__ enc,
                            const float* __restrict__ attn,
                            float* __restrict__ part) {
  int b = blockIdx.x >> 5, c = blockIdx.x & 31;
  int tid = threadIdx.x;
  __shared__ float aw[128];
  if (tid < 128) aw[tid] = attn[(size_t)b * S_ + c * 128 + tid];
  __syncthreads();
  const float* ebase = enc + ((size_t)b * S_ + c * 128) * H_ + tid * 2;
  float sx = 0.f, sy = 0.f;
  #pragma unroll 4
  for (int i = 0; i < 128; ++i) {
    float2 e = *(const float2*)(ebase + (size_t)i * H_);
    float a = aw[i];
    sx = fmaf(a, e.x, sx); sy = fmaf(a, e.y, sy);
  }
  float2 o; o.x = sx; o.y = sy;
  *(float2*)(part + ((size_t)(b * 32 + c)) * H_ + tid * 2) = o;
}

// ---------------- kernel 4: reduce partials -> context -------------------------
__global__ void ctx_reduce(const float* __restrict__ part,
                           float* __restrict__ ctx) {
  int b = blockIdx.x, tid = threadIdx.x;
  float sx = 0.f, sy = 0.f;
  #pragma unroll
  for (int c = 0; c < 32; ++c) {
    float2 p = *(const float2*)(part + ((size_t)(b * 32 + c)) * H_ + tid * 2);
    sx += p.x; sy += p.y;
  }
  float2 o; o.x = sx; o.y = sy;
  *(float2*)(ctx + (size_t)b * H_ + tid * 2) = o;
}

extern "C" void kernel_launch(void* const* d_in, const int* in_sizes, int n_in,
                              void* d_out, int out_size, void* d_ws, size_t ws_size,
                              hipStream_t stream) {
  const float* enc   = (const float*)d_in[0];
  const float* dh    = (const float*)d_in[1];
  const float* W_enc = (const float*)d_in[2];
  const float* b_enc = (const float*)d_in[3];
  const float* W_dec = (const float*)d_in[4];
  const float* b_dec = (const float*)d_in[5];
  const float* W_e   = (const float*)d_in[6];
  // b_e (d_in[7]) dropped: softmax is shift-invariant and scores are not an output.

  char* ws = (char*)d_ws;
  unsigned short* WT = (unsigned short*)(ws + WS_WT);
  float* bias   = (float*)(ws + WS_BIAS);
  float* scores = (float*)(ws + WS_SCORES);
  float* part   = (float*)(ws + WS_PART);

  float* ctx  = (float*)d_out;            // [32][512]
  float* attn = (float*)d_out + B_ * H_;  // [32][4096]

  prep_kernel<<<dim3(64), dim3(256), 0, stream>>>(dh, W_enc, b_enc, W_dec, b_dec, WT, bias);
  scores_gemm<<<dim3(1024), dim3(256), 0, stream>>>(enc, WT, bias, W_e, scores);
  softmax_kernel<<<dim3(32), dim3(256), 0, stream>>>(scores, attn);
  ctx_partial<<<dim3(1024), dim3(256), 0, stream>>>(enc, attn, part);
  ctx_reduce<<<dim3(32), dim3(256), 0, stream>>>(part, ctx);
}